// Round 9
// baseline (2454.498 us; speedup 1.0000x reference)
//
#include <hip/hip_runtime.h>

// ---------------------------------------------------------------------------
// Child-Sum TreeLSTM, complete binary tree, level-wise bottom-up, bf16 MFMA.
// Round 9 (= R8 + LDS-attribute safety): R2/R4/R7 all plateaued at ~380-400us
// on level 16 (HBM 8%, MFMA 11%, Occupancy ~23% = one 8-wave block/CU):
// latency-bound on per-tile weight re-fetch. Fix:
//   (1) MT=64, 1024-thread blocks (16 waves, 1 block/CU, LDS 99 KB via
//       hipFuncSetAttribute) -> halves weight bytes/node, 2x waves to hide
//       weight-load latency; per-thread structure = R7 (no spill, 104 VGPR)
//   (2) non-temporal loads/stores on ALL streaming data (x, hb, cb, outputs)
//       -> 1.05 MB weight set stays L2-resident
//   (3) grid = min(T,256) persistent blocks
//
// mfma_f32_32x32x16_bf16: A lane: row=l&31, k=(l>>5)*8+e  (16B ds_read)
//                         B lane: col=l&31, k=(l>>5)*8+e = W[col][k] (16B)
//                         D: col=l&31, row=(r&3)+8*(r>>2)+4*(l>>5), r=0..15
// ---------------------------------------------------------------------------

typedef __attribute__((ext_vector_type(8))) short bf16x8;
typedef __attribute__((ext_vector_type(8))) unsigned short us8;
typedef __attribute__((ext_vector_type(16))) float f32x16;
typedef __attribute__((ext_vector_type(4))) float f4;

#define LSTR 264   // 256 + 8 bf16 pad (row stride 528 B)
#define MT 64      // nodes per tile

#define MFMA32(A, B, C) __builtin_amdgcn_mfma_f32_32x32x16_bf16(A, B, C, 0, 0, 0)

__device__ __forceinline__ unsigned short f2b(float f) {
  unsigned int u = __builtin_bit_cast(unsigned int, f);
  u = u + 0x7FFFu + ((u >> 16) & 1u);   // RNE
  return (unsigned short)(u >> 16);
}
__device__ __forceinline__ float bf2f(unsigned short u) {
  unsigned int v = (unsigned int)u << 16;
  return __builtin_bit_cast(float, v);
}
__device__ __forceinline__ us8 pack8(f4 a, f4 b) {
  us8 r;
  r[0] = f2b(a[0]); r[1] = f2b(a[1]); r[2] = f2b(a[2]); r[3] = f2b(a[3]);
  r[4] = f2b(b[0]); r[5] = f2b(b[1]); r[6] = f2b(b[2]); r[7] = f2b(b[3]);
  return r;
}
__device__ __forceinline__ float sigm(float x) { return 1.0f / (1.0f + __expf(-x)); }
__device__ __forceinline__ float tanh_f(float x) { return 2.0f / (1.0f + __expf(-2.0f * x)) - 1.0f; }
__device__ __forceinline__ f32x16 zz16() {
  f32x16 v;
  #pragma unroll
  for (int i = 0; i < 16; ++i) v[i] = 0.f;
  return v;
}

__global__ void pack_w(const float* __restrict__ a,  // Wioux 768x256
                       const float* __restrict__ b,  // Wiouh 768x256
                       const float* __restrict__ c,  // Wfx   256x256
                       const float* __restrict__ d,  // Wfh   256x256
                       unsigned short* __restrict__ out) {
  int i = blockIdx.x * blockDim.x + threadIdx.x;  // 0 .. 524287
  const int A = 768 * 256;
  const int B = A + 768 * 256;
  const int C = B + 256 * 256;
  float v;
  if (i < A)      v = a[i];
  else if (i < B) v = b[i - A];
  else if (i < C) v = c[i - B];
  else            v = d[i - C];
  out[i] = f2b(v);
}

// convert interior-node x rows to bf16 (8 elems/thread), non-temporal
__global__ void conv_x(const float* __restrict__ x, unsigned short* __restrict__ xb, int n8) {
  int i = blockIdx.x * blockDim.x + threadIdx.x;
  if (i >= n8) return;
  f4 a = __builtin_nontemporal_load((const f4*)(x + (size_t)i * 8));
  f4 b = __builtin_nontemporal_load((const f4*)(x + (size_t)i * 8 + 4));
  __builtin_nontemporal_store(pack8(a, b), (us8*)(xb + (size_t)i * 8));
}

template<int LEAF>
__global__ __launch_bounds__(1024, 1) void level_k(
    const float* __restrict__ xf32,            // leaf path
    const unsigned short* __restrict__ xb,     // interior path (global node idx)
    const unsigned short* __restrict__ Wx,     // bf16 Wioux [768][256]
    const unsigned short* __restrict__ Wh,     // bf16 Wiouh [768][256]
    const unsigned short* __restrict__ Wfxw,   // bf16 Wfx   [256][256]
    const unsigned short* __restrict__ Wfhw,   // bf16 Wfh   [256][256]
    const float* __restrict__ bioux,
    const float* __restrict__ bfx,
    const float* __restrict__ fb,
    float* __restrict__ h_all,                 // d_out + 512, global node idx
    unsigned short* __restrict__ cb_cur,       // level-local [L][256] bf16
    const unsigned short* __restrict__ cb_next,
    unsigned short* __restrict__ hb_cur,
    const unsigned short* __restrict__ hb_next,
    float* __restrict__ out0,                  // d_out (h_root | c_root)
    int s, int L, int T, int root)
{
  extern __shared__ unsigned short sm[];
  unsigned short* Xs  = sm;                       // [MT][LSTR]
  unsigned short* H1s = sm + MT * LSTR;
  unsigned short* H2s = sm + 2 * MT * LSTR;

  const int tid = threadIdx.x;
  const int G   = gridDim.x;

  // staging partition: thread -> (row 0..63, 16-elem chunk)
  const int row = tid >> 4;
  const int ec  = (tid & 15) * 16;

  // MFMA ids: 16 waves = 2 row-halves x 8 col-groups
  const int lane = tid & 63;
  const int w    = tid >> 6;          // 0..15
  const int cg   = w & 7;             // col group
  const int rh   = w >> 3;            // row half (0..1)
  const int lr   = lane & 31;
  const int kh   = lane >> 5;
  const int koff = kh * 8;
  const int colc = cg * 32 + lr;
  const int arow = rh * 32 + lr;      // A-frag LDS row

  const unsigned short* wxp  = Wx   + (size_t)colc * 256;  // i (o:+65536, u:+131072)
  const unsigned short* whp  = Wh   + (size_t)colc * 256;
  const unsigned short* wfxp = Wfxw + (size_t)colc * 256;
  const unsigned short* wfhp = Wfhw + (size_t)colc * 256;

  const float bi_ = bioux[colc];
  const float bo_ = bioux[256 + colc];
  const float bu_ = bioux[512 + colc];
  const float bf_ = LEAF ? 0.f : (bfx[colc] + fb[colc]);

  // ---- staged registers ----
  us8 sx0, sx1, sh10, sh11, sh20, sh21;
  f4 fx0, fx1, fx2, fx3;

  int t = blockIdx.x;
  // prologue loads (non-temporal: pure stream)
  if (LEAF) {
    const float* xp = xf32 + ((size_t)(s + t * MT + row)) * 256 + ec;
    fx0 = __builtin_nontemporal_load((const f4*)xp);
    fx1 = __builtin_nontemporal_load((const f4*)(xp + 4));
    fx2 = __builtin_nontemporal_load((const f4*)(xp + 8));
    fx3 = __builtin_nontemporal_load((const f4*)(xp + 12));
  } else {
    const unsigned short* xq = xb + ((size_t)(s + t * MT + row)) * 256 + ec;
    sx0 = __builtin_nontemporal_load((const us8*)xq);
    sx1 = __builtin_nontemporal_load((const us8*)(xq + 8));
    const unsigned short* hq = hb_next + ((size_t)(2 * (t * MT + row))) * 256 + ec;
    sh10 = __builtin_nontemporal_load((const us8*)hq);
    sh11 = __builtin_nontemporal_load((const us8*)(hq + 8));
    sh20 = __builtin_nontemporal_load((const us8*)(hq + 256));
    sh21 = __builtin_nontemporal_load((const us8*)(hq + 264));
  }

  for (; t < T; t += G) {
    const int nb0 = t * MT;

    __syncthreads();   // prior tile's LDS readers done
    if (LEAF) {
      *(us8*)(Xs + row * LSTR + ec)     = pack8(fx0, fx1);
      *(us8*)(Xs + row * LSTR + ec + 8) = pack8(fx2, fx3);
    } else {
      *(us8*)(Xs  + row * LSTR + ec)     = sx0;
      *(us8*)(Xs  + row * LSTR + ec + 8) = sx1;
      *(us8*)(H1s + row * LSTR + ec)     = sh10;
      *(us8*)(H1s + row * LSTR + ec + 8) = sh11;
      *(us8*)(H2s + row * LSTR + ec)     = sh20;
      *(us8*)(H2s + row * LSTR + ec + 8) = sh21;
    }
    __syncthreads();   // LDS tile ready

    const int tn = t + G;
    float cv[16];

    if (!LEAF) {
      // ---- P1: axf = x @ Wfx^T (one plane live) ----
      f32x16 axf = zz16();
      #pragma unroll 2
      for (int kt = 0; kt < 16; ++kt) {
        const int k0 = kt * 16 + koff;
        bf16x8 bv = *(const bf16x8*)(wfxp + k0);
        bf16x8 av = *(const bf16x8*)(Xs + arow * LSTR + k0);
        axf = MFMA32(av, bv, axf);
      }

      // ---- c1 gather (hides under P2a) ----
      float c1v[16];
      #pragma unroll
      for (int r = 0; r < 16; ++r) {
        const int m = rh * 32 + (r & 3) + 8 * (r >> 2) + 4 * kh;
        c1v[r] = bf2f(__builtin_nontemporal_load(
            cb_next + (size_t)(2 * (nb0 + m)) * 256 + colc));
      }

      // ---- P2a: f1 = axf + h1@Wfh^T ----
      f32x16 f1 = axf;
      #pragma unroll 2
      for (int kt = 0; kt < 16; ++kt) {
        const int k0 = kt * 16 + koff;
        bf16x8 bv = *(const bf16x8*)(wfhp + k0);
        bf16x8 av = *(const bf16x8*)(H1s + arow * LSTR + k0);
        f1 = MFMA32(av, bv, f1);
      }
      #pragma unroll
      for (int r = 0; r < 16; ++r) cv[r] = sigm(f1[r] + bf_) * c1v[r];

      // ---- c2 gather (hides under P2b) ----
      float c2v[16];
      #pragma unroll
      for (int r = 0; r < 16; ++r) {
        const int m = rh * 32 + (r & 3) + 8 * (r >> 2) + 4 * kh;
        c2v[r] = bf2f(__builtin_nontemporal_load(
            cb_next + (size_t)(2 * (nb0 + m) + 1) * 256 + colc));
      }

      // ---- P2b: f2 = axf + h2@Wfh^T (axf reused as accumulator) ----
      #pragma unroll 2
      for (int kt = 0; kt < 16; ++kt) {
        const int k0 = kt * 16 + koff;
        bf16x8 bv = *(const bf16x8*)(wfhp + k0);
        bf16x8 av = *(const bf16x8*)(H2s + arow * LSTR + k0);
        axf = MFMA32(av, bv, axf);
      }
      #pragma unroll
      for (int r = 0; r < 16; ++r) cv[r] += sigm(axf[r] + bf_) * c2v[r];

      // ---- issue next tile's staged loads (land during P3) ----
      if (tn < T) {
        const unsigned short* xq = xb + ((size_t)(s + tn * MT + row)) * 256 + ec;
        sx0 = __builtin_nontemporal_load((const us8*)xq);
        sx1 = __builtin_nontemporal_load((const us8*)(xq + 8));
        const unsigned short* hq = hb_next + ((size_t)(2 * (tn * MT + row))) * 256 + ec;
        sh10 = __builtin_nontemporal_load((const us8*)hq);
        sh11 = __builtin_nontemporal_load((const us8*)(hq + 8));
        sh20 = __builtin_nontemporal_load((const us8*)(hq + 256));
        sh21 = __builtin_nontemporal_load((const us8*)(hq + 264));
      }

      // ---- P3i: ai = x@Wi_x + h1@Wi_h + h2@Wi_h ----
      f32x16 acc = zz16();
      #pragma unroll 1
      for (int kt = 0; kt < 16; ++kt) {
        const int k0 = kt * 16 + koff;
        bf16x8 bx = *(const bf16x8*)(wxp + k0);
        bf16x8 bh = *(const bf16x8*)(whp + k0);
        bf16x8 ax = *(const bf16x8*)(Xs  + arow * LSTR + k0);
        bf16x8 a1 = *(const bf16x8*)(H1s + arow * LSTR + k0);
        bf16x8 a2 = *(const bf16x8*)(H2s + arow * LSTR + k0);
        acc = MFMA32(ax, bx, acc);
        acc = MFMA32(a1, bh, acc);
        acc = MFMA32(a2, bh, acc);
      }
      float ig[16];
      #pragma unroll
      for (int r = 0; r < 16; ++r) ig[r] = sigm(acc[r] + bi_);

      // ---- P3u ----
      acc = zz16();
      #pragma unroll 1
      for (int kt = 0; kt < 16; ++kt) {
        const int k0 = kt * 16 + koff;
        bf16x8 bx = *(const bf16x8*)(wxp + 131072 + k0);
        bf16x8 bh = *(const bf16x8*)(whp + 131072 + k0);
        bf16x8 ax = *(const bf16x8*)(Xs  + arow * LSTR + k0);
        bf16x8 a1 = *(const bf16x8*)(H1s + arow * LSTR + k0);
        bf16x8 a2 = *(const bf16x8*)(H2s + arow * LSTR + k0);
        acc = MFMA32(ax, bx, acc);
        acc = MFMA32(a1, bh, acc);
        acc = MFMA32(a2, bh, acc);
      }
      #pragma unroll
      for (int r = 0; r < 16; ++r) cv[r] += ig[r] * tanh_f(acc[r] + bu_);

      // ---- P3o ----
      acc = zz16();
      #pragma unroll 1
      for (int kt = 0; kt < 16; ++kt) {
        const int k0 = kt * 16 + koff;
        bf16x8 bx = *(const bf16x8*)(wxp + 65536 + k0);
        bf16x8 bh = *(const bf16x8*)(whp + 65536 + k0);
        bf16x8 ax = *(const bf16x8*)(Xs  + arow * LSTR + k0);
        bf16x8 a1 = *(const bf16x8*)(H1s + arow * LSTR + k0);
        bf16x8 a2 = *(const bf16x8*)(H2s + arow * LSTR + k0);
        acc = MFMA32(ax, bx, acc);
        acc = MFMA32(a1, bh, acc);
        acc = MFMA32(a2, bh, acc);
      }

      // ---- epilogue (non-temporal stores) ----
      #pragma unroll
      for (int r = 0; r < 16; ++r) {
        const int m = rh * 32 + (r & 3) + 8 * (r >> 2) + 4 * kh;
        const int j = nb0 + m;
        if (j >= L) continue;
        const size_t n = (size_t)(s + j);
        const float c_ = cv[r];
        const float hv = sigm(acc[r] + bo_) * tanh_f(c_);
        __builtin_nontemporal_store(hv, h_all + n * 256 + colc);
        __builtin_nontemporal_store(f2b(c_), cb_cur + (size_t)j * 256 + colc);
        __builtin_nontemporal_store(f2b(hv), hb_cur + (size_t)j * 256 + colc);
        if (root && j == 0) { out0[colc] = hv; out0[256 + colc] = c_; }
      }
    } else {
      // ---- leaf: issue next staged loads, then per-gate passes on x ----
      if (tn < T) {
        const float* xp = xf32 + ((size_t)(s + tn * MT + row)) * 256 + ec;
        fx0 = __builtin_nontemporal_load((const f4*)xp);
        fx1 = __builtin_nontemporal_load((const f4*)(xp + 4));
        fx2 = __builtin_nontemporal_load((const f4*)(xp + 8));
        fx3 = __builtin_nontemporal_load((const f4*)(xp + 12));
      }

      f32x16 acc = zz16();
      #pragma unroll 1
      for (int kt = 0; kt < 16; ++kt) {
        const int k0 = kt * 16 + koff;
        bf16x8 bx = *(const bf16x8*)(wxp + k0);
        bf16x8 ax = *(const bf16x8*)(Xs + arow * LSTR + k0);
        acc = MFMA32(ax, bx, acc);
      }
      float ig[16];
      #pragma unroll
      for (int r = 0; r < 16; ++r) ig[r] = sigm(acc[r] + bi_);

      acc = zz16();
      #pragma unroll 1
      for (int kt = 0; kt < 16; ++kt) {
        const int k0 = kt * 16 + koff;
        bf16x8 bx = *(const bf16x8*)(wxp + 131072 + k0);
        bf16x8 ax = *(const bf16x8*)(Xs + arow * LSTR + k0);
        acc = MFMA32(ax, bx, acc);
      }
      #pragma unroll
      for (int r = 0; r < 16; ++r) cv[r] = ig[r] * tanh_f(acc[r] + bu_);

      acc = zz16();
      #pragma unroll 1
      for (int kt = 0; kt < 16; ++kt) {
        const int k0 = kt * 16 + koff;
        bf16x8 bx = *(const bf16x8*)(wxp + 65536 + k0);
        bf16x8 ax = *(const bf16x8*)(Xs + arow * LSTR + k0);
        acc = MFMA32(ax, bx, acc);
      }

      #pragma unroll
      for (int r = 0; r < 16; ++r) {
        const int m = rh * 32 + (r & 3) + 8 * (r >> 2) + 4 * kh;
        const int j = nb0 + m;
        if (j >= L) continue;
        const size_t n = (size_t)(s + j);
        const float c_ = cv[r];
        const float hv = sigm(acc[r] + bo_) * tanh_f(c_);
        __builtin_nontemporal_store(hv, h_all + n * 256 + colc);
        __builtin_nontemporal_store(f2b(c_), cb_cur + (size_t)j * 256 + colc);
        __builtin_nontemporal_store(f2b(hv), hb_cur + (size_t)j * 256 + colc);
      }
    }
  }
}

extern "C" void kernel_launch(void* const* d_in, const int* in_sizes, int n_in,
                              void* d_out, int out_size, void* d_ws, size_t ws_size,
                              hipStream_t stream) {
  const float* inputs = (const float*)d_in[0];
  const float* Wioux  = (const float*)d_in[1];
  const float* bioux  = (const float*)d_in[2];
  const float* Wiouh  = (const float*)d_in[3];
  const float* Wfx    = (const float*)d_in[4];
  const float* bfx    = (const float*)d_in[5];
  const float* Wfh    = (const float*)d_in[6];
  const float* fb     = (const float*)d_in[7];

  const int N = in_sizes[0] / 256;       // 262143
  int depth = 0;
  while (((1 << depth) - 1) < N) ++depth;  // 18
  const int LF = (N + 1) / 2;            // 131072 leaves

  float* out   = (float*)d_out;
  float* h_all = out + 512;

  // allow >64KB dynamic LDS for the interior kernel (99 KB); harmless if
  // already allowed. Host-side attribute set — graph-capture safe.
  static bool attr_done = false;
  if (!attr_done) {
    hipFuncSetAttribute((const void*)level_k<0>,
                        hipFuncAttributeMaxDynamicSharedMemorySize, 3 * MT * LSTR * 2);
    hipFuncSetAttribute((const void*)level_k<1>,
                        hipFuncAttributeMaxDynamicSharedMemorySize, MT * LSTR * 2);
    attr_done = true;
  }

  // ws carve (bytes): cb ping-pong bf16, hb ping-pong bf16, xb bf16, weights
  char* p = (char*)d_ws;
  unsigned short* cb_even = (unsigned short*)p; p += (size_t)(LF / 2) * 256 * 2;
  unsigned short* cb_odd  = (unsigned short*)p; p += (size_t)LF * 256 * 2;
  unsigned short* hb_even = (unsigned short*)p; p += (size_t)(LF / 2) * 256 * 2;
  unsigned short* hb_odd  = (unsigned short*)p; p += (size_t)LF * 256 * 2;
  unsigned short* xb      = (unsigned short*)p; p += (size_t)LF * 256 * 2;
  unsigned short* wb      = (unsigned short*)p;

  pack_w<<<2048, 256, 0, stream>>>(Wioux, Wiouh, Wfx, Wfh, wb);
  {
    const int n8 = ((LF - 1) * 256) / 8;   // interior-node elems / 8
    conv_x<<<(n8 + 255) / 256, 256, 0, stream>>>(inputs, xb, n8);
  }

  const unsigned short* pWx  = wb;
  const unsigned short* pWh  = wb + 768 * 256;
  const unsigned short* pWfx = wb + 2 * 768 * 256;
  const unsigned short* pWfh = wb + 2 * 768 * 256 + 256 * 256;

  for (int d = depth - 1; d >= 0; --d) {
    const int L = 1 << d;
    const int s = L - 1;
    const int T = (L + MT - 1) / MT;
    const int G = T < 256 ? T : 256;
    unsigned short* cb_cur = (d & 1) ? cb_odd : cb_even;
    const unsigned short* cb_next = ((d + 1) & 1) ? cb_odd : cb_even;
    unsigned short* hb_cur = (d & 1) ? hb_odd : hb_even;
    const unsigned short* hb_next = ((d + 1) & 1) ? hb_odd : hb_even;
    if (d == depth - 1) {
      level_k<1><<<G, 1024, (size_t)MT * LSTR * 2, stream>>>(
          inputs, xb, pWx, pWh, pWfx, pWfh, bioux, bfx, fb,
          h_all, cb_cur, cb_next, hb_cur, hb_next, out, s, L, T, 0);
    } else {
      level_k<0><<<G, 1024, (size_t)3 * MT * LSTR * 2, stream>>>(
          inputs, xb, pWx, pWh, pWfx, pWfh, bioux, bfx, fb,
          h_all, cb_cur, cb_next, hb_cur, hb_next, out, s, L, T, (d == 0) ? 1 : 0);
    }
  }
}